// Round 4
// baseline (636.073 us; speedup 1.0000x reference)
//
#include <hip/hip_runtime.h>
#include <cstddef>

#define N_ 4
#define D_ 16
#define H_ 128
#define W_ 128
#define K_ 24
#define L_ 6
#define NTAP_A 13
#define NTAP_B 14

// intermediate layout: [n][d][h][g=ci/4][w][4]   (float4 per (g,w))
#define GS 512    // g stride (floats) = 128*4
#define HS 3072   // h stride = 6*512

// workspace layout (float offsets)
#define OFF_Q   0u
#define OFF_TGT 1048576u
#define OFF_H0  2097152u
#define OFF_H1  27262976u
#define OFF_W0P 52428800u
#define OFF_W1P 52429312u
#define OFF_W2P 52437504u

// ---------------------------------------------------------------- pack weights
// w1p/w2p layout: [t][ci][co] (t = raster tap index; uniform runtime base,
// compile-time ci/co offsets -> s_load)
__global__ void pack_weights_k(const float* __restrict__ w0,
                               const float* __restrict__ w1,
                               const float* __restrict__ w2,
                               float* __restrict__ w0p,
                               float* __restrict__ w1p,
                               float* __restrict__ w2p) {
  int tid = threadIdx.x;
  for (int i = tid; i < NTAP_A * K_; i += 256) {
    int co = i % K_;
    int t  = i / K_;
    w0p[t * K_ + co] = w0[co * 27 + t];
  }
  for (int i = tid; i < K_ * NTAP_B * K_; i += 256) {
    int co = i % K_;
    int ci = (i / K_) % K_;
    int t  = i / (K_ * K_);
    w1p[i] = w1[(co * K_ + ci) * 27 + t];
    w2p[i] = w2[(co * K_ + ci) * 27 + t];
  }
}

// ---------------------------------------------------------------- quantize
__global__ __launch_bounds__(256) void quantize_k(
    const float* __restrict__ x, const float* __restrict__ centers,
    float* __restrict__ qbar_out, float* __restrict__ q,
    int* __restrict__ tgt) {
  int idx = blockIdx.x * 256 + threadIdx.x;  // over [n][c][h][w]
  int w = idx & 127;
  int h = (idx >> 7) & 127;
  int c = (idx >> 14) & 15;
  int n = idx >> 18;

  float cs[L_];
#pragma unroll
  for (int l = 0; l < L_; ++l) cs[l] = centers[l];

  int xi = ((n * H_ + h) * W_ + w) * D_ + c;  // NHWC
  float xv = x[xi];

  float dv[L_];
  float dmin = 3.4e38f;
  int sym = 0;
#pragma unroll
  for (int l = 0; l < L_; ++l) {
    float df = xv - cs[l];
    float d = df * df;
    dv[l] = d;
    if (d < dmin) { dmin = d; sym = l; }
  }
  float e[L_];
  float s = 0.f;
#pragma unroll
  for (int l = 0; l < L_; ++l) {
    e[l] = expf(dmin - dv[l]);
    s += e[l];
  }
  float qsoft = 0.f;
#pragma unroll
  for (int l = 0; l < L_; ++l) qsoft += (e[l] / s) * cs[l];

  float qhard = cs[sym];
  float qb = qsoft + (qhard - qsoft);

  qbar_out[xi] = qb;
  q[idx] = qb;  // [n][d][h][w]
  tgt[idx] = sym;
}

// ---------------------------------------------------------------- conv0 (1 -> 24, 13 taps, pad = centers[0])
__global__ __launch_bounds__(256) void conv0_k(
    const float* __restrict__ q, const float* __restrict__ w0p,
    const float* __restrict__ b0, const float* __restrict__ centers,
    float* __restrict__ h0) {
  float pv = centers[0];

  int blk = blockIdx.x;  // 4096 = 64 h-pairs * 16 d * 4 n
  int h2 = blk & 63;
  int d = (blk >> 6) & 15;
  int n = blk >> 10;
  int w = threadIdx.x & 127;
  int h = (h2 << 1) | (threadIdx.x >> 7);

  float acc[K_];
#pragma unroll
  for (int i = 0; i < K_; ++i) acc[i] = b0[i];

  const float* base = q + ((n * D_ + d) * H_ + h) * W_ + w;

#pragma unroll 1
  for (int t = 0; t < NTAP_A; ++t) {
    int dz = t / 9 - 1;
    int r = t % 9;
    int dy = r / 3 - 1;
    int dx = r % 3 - 1;
    int hh = h + dy, ww = w + dx, dd = d + dz;
    bool ok = (dd >= 0) && ((unsigned)hh < H_) && ((unsigned)ww < W_);
    float xv = ok ? base[(dz * H_ + dy) * W_ + dx] : pv;
    const float* wr = w0p + t * K_;
#pragma unroll
    for (int co = 0; co < K_; ++co) acc[co] = fmaf(xv, wr[co], acc[co]);
  }

  // store in [g][w][4] layout
  float* dst = h0 + (size_t)((n * D_ + d) * H_ + h) * HS + w * 4;
#pragma unroll
  for (int g = 0; g < 6; ++g) {
    float4 v = make_float4(fmaxf(acc[4 * g], 0.f), fmaxf(acc[4 * g + 1], 0.f),
                           fmaxf(acc[4 * g + 2], 0.f), fmaxf(acc[4 * g + 3], 0.f));
    *(float4*)(dst + g * GS) = v;
  }
}

// ---------------------------------------------------------------- 24->24 masked-B conv, P=4 w-blocked
// src layout [n][d][h][g][w][4]; weights [t][ci][co] via scalar loads.
__device__ __forceinline__ void conv14_acc4(const float* __restrict__ src,
                                            const float* __restrict__ wp,
                                            const float* __restrict__ b,
                                            int n, int d, int h, int w0,
                                            float acc[4][K_]) {
#pragma unroll
  for (int p = 0; p < 4; ++p)
#pragma unroll
    for (int i = 0; i < K_; ++i) acc[p][i] = b[i];

  bool wlo = (w0 > 0);      // position w0-1 valid
  bool whi = (w0 < 124);    // position w0+4 valid

  // full rows: (dz,dy) = (-1,-1),(-1,0),(-1,1),(0,-1), taps tb..tb+2 (dx=-1,0,1)
#pragma unroll 1
  for (int row = 0; row < 4; ++row) {
    int dz = (row < 3) ? -1 : 0;
    int dy = (row < 3) ? (row - 1) : -1;
    int dd = d + dz, hh = h + dy;
    bool rowOK = (dd >= 0) && ((unsigned)hh < (unsigned)H_);
    const float* rp = src + (size_t)((n * D_ + dd) * H_ + hh) * HS + (w0 - 1) * 4;
    int tb = row * 3;
#pragma unroll 1
    for (int g = 0; g < 6; ++g) {
      const float* gp = rp + g * GS;
      float4 xq[6];
#pragma unroll
      for (int j = 0; j < 6; ++j) {
        bool ok = rowOK && (j != 0 || wlo) && (j != 5 || whi);
        xq[j] = ok ? *(const float4*)(gp + j * 4) : make_float4(0.f, 0.f, 0.f, 0.f);
      }
#pragma unroll
      for (int ci4 = 0; ci4 < 4; ++ci4) {
#pragma unroll
        for (int dxi = 0; dxi < 3; ++dxi) {
          const float* wr = wp + (size_t)((tb + dxi) * K_ + g * 4 + ci4) * K_;
#pragma unroll
          for (int p = 0; p < 4; ++p) {
            float xs = ((const float*)&xq[p + dxi])[ci4];
#pragma unroll
            for (int co = 0; co < K_; ++co)
              acc[p][co] = fmaf(xs, wr[co], acc[p][co]);
          }
        }
      }
    }
  }

  // partial row: (dz,dy)=(0,0), taps 12,13 (dx=-1,0)
  {
    const float* rp = src + (size_t)((n * D_ + d) * H_ + h) * HS + (w0 - 1) * 4;
#pragma unroll 1
    for (int g = 0; g < 6; ++g) {
      const float* gp = rp + g * GS;
      float4 xq[5];
#pragma unroll
      for (int j = 0; j < 5; ++j) {
        bool ok = (j != 0 || wlo);
        xq[j] = ok ? *(const float4*)(gp + j * 4) : make_float4(0.f, 0.f, 0.f, 0.f);
      }
#pragma unroll
      for (int ci4 = 0; ci4 < 4; ++ci4) {
#pragma unroll
        for (int dxi = 0; dxi < 2; ++dxi) {
          const float* wr = wp + (size_t)((12 + dxi) * K_ + g * 4 + ci4) * K_;
#pragma unroll
          for (int p = 0; p < 4; ++p) {
            float xs = ((const float*)&xq[p + dxi])[ci4];
#pragma unroll
            for (int co = 0; co < K_; ++co)
              acc[p][co] = fmaf(xs, wr[co], acc[p][co]);
          }
        }
      }
    }
  }
}

// ---------------------------------------------------------------- conv1 (24->24, relu)
__global__ __launch_bounds__(256, 2) void conv1_k(const float* __restrict__ src,
                                                  const float* __restrict__ wp,
                                                  const float* __restrict__ b,
                                                  float* __restrict__ dst) {
  int blk = blockIdx.x;          // 1024 = 16 hgrp * 16 d * 4 n
  int w0 = (threadIdx.x & 31) * 4;
  int h = ((blk & 15) << 3) | (threadIdx.x >> 5);
  int d = (blk >> 4) & 15;
  int n = blk >> 8;

  float acc[4][K_];
  conv14_acc4(src, wp, b, n, d, h, w0, acc);

  float* ob = dst + (size_t)((n * D_ + d) * H_ + h) * HS + w0 * 4;
#pragma unroll
  for (int g = 0; g < 6; ++g) {
#pragma unroll
    for (int p = 0; p < 4; ++p) {
      float4 v = make_float4(
          fmaxf(acc[p][4 * g], 0.f), fmaxf(acc[p][4 * g + 1], 0.f),
          fmaxf(acc[p][4 * g + 2], 0.f), fmaxf(acc[p][4 * g + 3], 0.f));
      *(float4*)(ob + g * GS + p * 4) = v;
    }
  }
}

// ---------------------------------------------------------------- conv2 + residual + relu + logits + bitcost
__global__ __launch_bounds__(256, 2) void conv2_bc_k(
    const float* __restrict__ h1, const float* __restrict__ h0,
    const float* __restrict__ w2p, const float* __restrict__ b2,
    const float* __restrict__ w_out, const float* __restrict__ b_out,
    const int* __restrict__ tgt, float* __restrict__ bco) {
  int blk = blockIdx.x;
  int w0 = (threadIdx.x & 31) * 4;
  int h = ((blk & 15) << 3) | (threadIdx.x >> 5);
  int d = (blk >> 4) & 15;
  int n = blk >> 8;

  float acc[4][K_];
  conv14_acc4(h1, w2p, b2, n, d, h, w0, acc);

  // residual + relu
  const float* hb = h0 + (size_t)((n * D_ + d) * H_ + h) * HS + w0 * 4;
#pragma unroll
  for (int g = 0; g < 6; ++g) {
#pragma unroll
    for (int p = 0; p < 4; ++p) {
      float4 r = *(const float4*)(hb + g * GS + p * 4);
      acc[p][4 * g]     = fmaxf(acc[p][4 * g]     + r.x, 0.f);
      acc[p][4 * g + 1] = fmaxf(acc[p][4 * g + 1] + r.y, 0.f);
      acc[p][4 * g + 2] = fmaxf(acc[p][4 * g + 2] + r.z, 0.f);
      acc[p][4 * g + 3] = fmaxf(acc[p][4 * g + 3] + r.w, 0.f);
    }
  }

  int posbase = ((n * D_ + d) * H_ + h) * W_ + w0;
  int4 t4 = *(const int4*)(tgt + posbase);

#pragma unroll
  for (int p = 0; p < 4; ++p) {
    float lg[L_];
#pragma unroll
    for (int l = 0; l < L_; ++l) lg[l] = b_out[l];
#pragma unroll
    for (int k = 0; k < K_; ++k) {
      float rv = acc[p][k];
#pragma unroll
      for (int l = 0; l < L_; ++l) lg[l] = fmaf(rv, w_out[l * K_ + k], lg[l]);
    }
    float m = lg[0];
#pragma unroll
    for (int l = 1; l < L_; ++l) m = fmaxf(m, lg[l]);
    float s = 0.f;
#pragma unroll
    for (int l = 0; l < L_; ++l) s += expf(lg[l] - m);

    int t = (p == 0) ? t4.x : (p == 1) ? t4.y : (p == 2) ? t4.z : t4.w;
    float lt = lg[0];
#pragma unroll
    for (int l = 1; l < L_; ++l) lt = (t == l) ? lg[l] : lt;

    float lp = lt - m - logf(s);
    bco[(size_t)(((n * H_ + h) * W_ + w0 + p)) * D_ + d] =
        -lp / 0.69314718055994530942f;
  }
}

// ---------------------------------------------------------------- launch
extern "C" void kernel_launch(void* const* d_in, const int* in_sizes, int n_in,
                              void* d_out, int out_size, void* d_ws, size_t ws_size,
                              hipStream_t stream) {
  const float* x       = (const float*)d_in[0];
  const float* centers = (const float*)d_in[1];
  const float* w0      = (const float*)d_in[2];
  const float* b0      = (const float*)d_in[3];
  const float* w1      = (const float*)d_in[4];
  const float* b1      = (const float*)d_in[5];
  const float* w2      = (const float*)d_in[6];
  const float* b2      = (const float*)d_in[7];
  const float* w_out   = (const float*)d_in[8];
  const float* b_out   = (const float*)d_in[9];
  float* out = (float*)d_out;

  float* ws  = (float*)d_ws;
  float* q   = ws + OFF_Q;
  int*   tg  = (int*)(ws + OFF_TGT);
  float* h0  = ws + OFF_H0;
  float* h1  = ws + OFF_H1;
  float* w0p = ws + OFF_W0P;
  float* w1p = ws + OFF_W1P;
  float* w2p = ws + OFF_W2P;

  hipLaunchKernelGGL(pack_weights_k, dim3(1), dim3(256), 0, stream,
                     w0, w1, w2, w0p, w1p, w2p);
  hipLaunchKernelGGL(quantize_k, dim3(4096), dim3(256), 0, stream,
                     x, centers, out, q, tg);
  hipLaunchKernelGGL(conv0_k, dim3(4096), dim3(256), 0, stream,
                     q, w0p, b0, centers, h0);
  hipLaunchKernelGGL(conv1_k, dim3(1024), dim3(256), 0, stream,
                     h0, w1p, b1, h1);
  hipLaunchKernelGGL(conv2_bc_k, dim3(1024), dim3(256), 0, stream,
                     h1, h0, w2p, b2, w_out, b_out, tg, out + 1048576);
}

// Round 5
// 220.031 us; speedup vs baseline: 2.8908x; 2.8908x over previous
//
#include <hip/hip_runtime.h>
#include <cstddef>

typedef _Float16 f16;
typedef _Float16 f16x8 __attribute__((ext_vector_type(8)));
typedef float f32x16 __attribute__((ext_vector_type(16)));

#define N_ 4
#define D_ 16
#define H_ 128
#define W_ 128
#define K_ 24
#define L_ 6
#define NTAP_A 13

// workspace byte offsets
#define OFF_Q    0ull          // f32 [n][d][h][w]
#define OFF_TGT  4194304ull    // i32 [n][d][h][w]
#define OFF_H0   8388608ull    // f16 [n][d][h][w][24]
#define OFF_H1   58720256ull   // f16 [n][d][h][w][24]
#define OFF_W0P  109051904ull  // f32 [13][24]
#define OFF_W1B  109053952ull  // f16 fragments, 10752 halves
#define OFF_W2B  109075456ull

// LDS geometry (bytes)
#define AROW_B 6336            // 132 pos * 48B
#define A_HALVES 22176         // 7 * 3168
#define B_HALVES 10752         // 21 chunks * 512
#define E_HALVES 6144          // 256 pos * 24

// A-tile byte offset for chunk (p,c) and lane-half g (hs*6336 added at runtime)
__host__ __device__ constexpr int aoff(int p, int c, int g) {
  int idx8 = 2 * c + g;
  int ts = idx8 >= 3 ? 1 : 0;
  int t = 2 * p + ts;            // raster tap 0..13 (mask B)
  int cb = idx8 - 3 * ts;        // ci block of 8
  int dz = t / 9 - 1;
  int rr = t % 9;
  int dy = rr / 3 - 1;
  int dx = rr % 3 - 1;
  int rowb = (dz < 0) ? (dy + 1) : (4 + dy + 1);
  return rowb * AROW_B + (dx + 1) * 48 + cb * 16;
}

// ---------------------------------------------------------------- pack weights
__global__ void pack_weights_k(const float* __restrict__ w0,
                               const float* __restrict__ w1,
                               const float* __restrict__ w2,
                               float* __restrict__ w0p,
                               f16* __restrict__ w1B,
                               f16* __restrict__ w2B) {
  int tid = threadIdx.x;
  // w0: [24][1][27] -> w0p[t][co], t<13 (mask A)
  for (int i = tid; i < NTAP_A * K_; i += 256) {
    int co = i % K_;
    int t  = i / K_;
    w0p[t * K_ + co] = w0[co * 27 + t];
  }
  // B fragments: halves idx = chunk*512 + g*256 + n*8 + j
  for (int i = tid; i < 2 * B_HALVES; i += 256) {
    int sel = i / B_HALVES;
    int idx = i % B_HALVES;
    int chunk = idx / 512;
    int r = idx % 512;
    int g = r / 256;
    int n = (r % 256) / 8;
    int j = r % 8;
    int p = chunk / 3, c = chunk % 3;
    int idx8 = 2 * c + g;
    int ts = idx8 >= 3 ? 1 : 0;
    int t = 2 * p + ts;
    int ci = (idx8 - 3 * ts) * 8 + j;
    const float* w = sel ? w2 : w1;
    float v = (n < K_) ? w[(n * K_ + ci) * 27 + t] : 0.f;
    (sel ? w2B : w1B)[idx] = (f16)v;
  }
}

// ---------------------------------------------------------------- quantize
__global__ __launch_bounds__(256) void quantize_k(
    const float* __restrict__ x, const float* __restrict__ centers,
    float* __restrict__ qbar_out, float* __restrict__ q,
    int* __restrict__ tgt) {
  int idx = blockIdx.x * 256 + threadIdx.x;  // over [n][c][h][w]
  int w = idx & 127;
  int h = (idx >> 7) & 127;
  int c = (idx >> 14) & 15;
  int n = idx >> 18;

  float cs[L_];
#pragma unroll
  for (int l = 0; l < L_; ++l) cs[l] = centers[l];

  int xi = ((n * H_ + h) * W_ + w) * D_ + c;  // NHWC
  float xv = x[xi];

  float dv[L_];
  float dmin = 3.4e38f;
  int sym = 0;
#pragma unroll
  for (int l = 0; l < L_; ++l) {
    float df = xv - cs[l];
    float d = df * df;
    dv[l] = d;
    if (d < dmin) { dmin = d; sym = l; }
  }
  float e[L_];
  float s = 0.f;
#pragma unroll
  for (int l = 0; l < L_; ++l) {
    e[l] = expf(dmin - dv[l]);
    s += e[l];
  }
  float qsoft = 0.f;
#pragma unroll
  for (int l = 0; l < L_; ++l) qsoft += (e[l] / s) * cs[l];

  float qhard = cs[sym];
  float qb = qsoft + (qhard - qsoft);

  qbar_out[xi] = qb;
  q[idx] = qb;  // [n][d][h][w]
  tgt[idx] = sym;
}

// ---------------------------------------------------------------- conv0 (1->24, 13 taps, pad=centers[0]) -> fp16 out
__global__ __launch_bounds__(256) void conv0_k(
    const float* __restrict__ q, const float* __restrict__ w0p,
    const float* __restrict__ b0, const float* __restrict__ centers,
    f16* __restrict__ h0) {
  float pv = centers[0];

  int blk = blockIdx.x;  // 4096 = 64 h-pairs * 16 d * 4 n
  int h2 = blk & 63;
  int d = (blk >> 6) & 15;
  int n = blk >> 10;
  int w = threadIdx.x & 127;
  int h = (h2 << 1) | (threadIdx.x >> 7);

  float acc[K_];
#pragma unroll
  for (int i = 0; i < K_; ++i) acc[i] = b0[i];

  const float* base = q + ((n * D_ + d) * H_ + h) * W_ + w;

#pragma unroll 1
  for (int t = 0; t < NTAP_A; ++t) {
    int dz = t / 9 - 1;
    int r = t % 9;
    int dy = r / 3 - 1;
    int dx = r % 3 - 1;
    int hh = h + dy, ww = w + dx, dd = d + dz;
    bool ok = (dd >= 0) && ((unsigned)hh < H_) && ((unsigned)ww < W_);
    float xv = ok ? base[(dz * H_ + dy) * W_ + dx] : pv;
    const float* wr = w0p + t * K_;
#pragma unroll
    for (int co = 0; co < K_; ++co) acc[co] = fmaf(xv, wr[co], acc[co]);
  }

  union { f16 hv[24]; uint4 u[3]; } u;
#pragma unroll
  for (int i = 0; i < K_; ++i) u.hv[i] = (f16)fmaxf(acc[i], 0.f);
  size_t pos = (size_t)(((n * D_ + d) * H_ + h) * W_ + w);
  uint4* dst = (uint4*)(h0 + pos * K_);
  dst[0] = u.u[0]; dst[1] = u.u[1]; dst[2] = u.u[2];
}

// ---------------------------------------------------------------- MFMA conv core (stage + K-loop)
__device__ __forceinline__ f32x16 conv_core(const f16* __restrict__ src,
                                            const f16* __restrict__ wB,
                                            f16* ldsA, f16* ldsB,
                                            int n, int d, int h_base) {
  const int tid = threadIdx.x;
  // stage B fragments (21504 B)
  {
    const uint4* g = (const uint4*)wB;
    uint4* s = (uint4*)ldsB;
    for (int i = tid; i < 1344; i += 512) s[i] = g[i];
  }
  // stage A rows: r<4: plane d-1, h_base-1+r ; r>=4: plane d, h_base-1+(r-4)
#pragma unroll
  for (int it = 0; it < 6; ++it) {
    int i = it * 512 + tid;
    if (i < 2688) {
      int r = i / 384, qq = i % 384;
      int dd = (r < 4) ? d - 1 : d;
      int hh = h_base - 1 + ((r < 4) ? r : r - 4);
      uint4 v = make_uint4(0, 0, 0, 0);
      if (dd >= 0 && hh >= 0 && hh < H_) {
        const uint4* g = (const uint4*)(src + (size_t)((n * D_ + dd) * H_ + hh) * 3072);
        v = g[qq];
      }
      *(uint4*)((char*)ldsA + r * AROW_B + 48 + qq * 16) = v;
    }
  }
  if (tid < 42) {  // halo zero: slots w=-1 and w=128 per row
    int r = tid / 6, k = tid % 6;
    int byte = r * AROW_B + (k < 3 ? k * 16 : 6192 + (k - 3) * 16);
    *(uint4*)((char*)ldsA + byte) = make_uint4(0, 0, 0, 0);
  }
  __syncthreads();

  const int lane = tid & 63;
  const int wv = tid >> 6;
  const int hs = wv >> 2;
  const int wbase = (wv & 3) * 32;
  const int m = lane & 31;
  const int g01 = lane >> 5;

  const char* Ab = (char*)ldsA + hs * AROW_B + (wbase + m) * 48;
  const char* Bb = (char*)ldsB + g01 * 512 + m * 16;

  f32x16 acc;
#pragma unroll
  for (int r = 0; r < 16; ++r) acc[r] = 0.f;

#pragma unroll
  for (int p = 0; p < 7; ++p) {
#pragma unroll
    for (int c = 0; c < 3; ++c) {
      constexpr int dummy = 0; (void)dummy;
      const int C0 = aoff(p, c, 0);
      const int C1 = aoff(p, c, 1);
      f16x8 a = *(const f16x8*)(Ab + (g01 ? C1 : C0));
      f16x8 b = *(const f16x8*)(Bb + (p * 3 + c) * 1024);
      acc = __builtin_amdgcn_mfma_f32_32x32x16_f16(a, b, acc, 0, 0, 0);
    }
  }
  return acc;
}

// ---------------------------------------------------------------- conv1 (h0 -> h1, relu)
__global__ __launch_bounds__(512) void conv1_mfma_k(
    const f16* __restrict__ src, const f16* __restrict__ wB,
    const float* __restrict__ bias, f16* __restrict__ dst) {
  __shared__ f16 ldsA[A_HALVES];
  __shared__ f16 ldsB[B_HALVES];
  __shared__ f16 ldsE[E_HALVES];

  int blk = blockIdx.x;          // 4096 = 64 hb * 16 d * 4 n  (hb fastest)
  int hb = blk & 63;
  int d = (blk >> 6) & 15;
  int n = blk >> 10;
  int h_base = hb * 2;

  f32x16 acc = conv_core(src, wB, ldsA, ldsB, n, d, h_base);

  const int lane = threadIdx.x & 63;
  const int wv = threadIdx.x >> 6;
  const int hs = wv >> 2;
  const int wbase = (wv & 3) * 32;
  const int co = lane & 31;
  const int g01 = lane >> 5;

  if (co < K_) {
    float bv = bias[co];
#pragma unroll
    for (int r = 0; r < 16; ++r) {
      int mrow = (r & 3) + 8 * (r >> 2) + 4 * g01;
      int pos = hs * 128 + wbase + mrow;
      ldsE[pos * K_ + co] = (f16)fmaxf(acc[r] + bv, 0.f);
    }
  }
  __syncthreads();
  {
    uint4* g = (uint4*)(dst + (size_t)((n * D_ + d) * H_ + h_base) * 3072);
    const uint4* s = (const uint4*)ldsE;
    for (int i = threadIdx.x; i < 768; i += 512) g[i] = s[i];
  }
}

// ---------------------------------------------------------------- conv2 + residual + relu + logits + bitcost
__global__ __launch_bounds__(512) void conv2_mfma_k(
    const f16* __restrict__ h1, const f16* __restrict__ h0,
    const f16* __restrict__ wB, const float* __restrict__ bias,
    const float* __restrict__ w_out, const float* __restrict__ b_out,
    const int* __restrict__ tgt, float* __restrict__ bco) {
  __shared__ f16 ldsA[A_HALVES];
  __shared__ f16 ldsB[B_HALVES];
  __shared__ f16 ldsE[E_HALVES];

  int blk = blockIdx.x;
  int hb = blk & 63;
  int d = (blk >> 6) & 15;
  int n = blk >> 10;
  int h_base = hb * 2;

  f32x16 acc = conv_core(h1, wB, ldsA, ldsB, n, d, h_base);

  // stage h0 2-row block into ldsE
  {
    const uint4* g = (const uint4*)(h0 + (size_t)((n * D_ + d) * H_ + h_base) * 3072);
    uint4* s = (uint4*)ldsE;
    for (int i = threadIdx.x; i < 768; i += 512) s[i] = g[i];
  }
  __syncthreads();

  const int lane = threadIdx.x & 63;
  const int wv = threadIdx.x >> 6;
  const int hs = wv >> 2;
  const int wbase = (wv & 3) * 32;
  const int co = lane & 31;
  const int g01 = lane >> 5;

  if (co < K_) {
    float bv = bias[co];
#pragma unroll
    for (int r = 0; r < 16; ++r) {
      int mrow = (r & 3) + 8 * (r >> 2) + 4 * g01;
      int pos = hs * 128 + wbase + mrow;
      float h0v = (float)ldsE[pos * K_ + co];
      ldsE[pos * K_ + co] = (f16)fmaxf(acc[r] + bv + h0v, 0.f);
    }
  }
  __syncthreads();

  if (threadIdx.x < 256) {
    int pos = threadIdx.x;
    int hh = h_base + (pos >> 7);
    int w = pos & 127;

    const f16x8* ep = (const f16x8*)(ldsE + pos * K_);
    f16x8 e0 = ep[0], e1 = ep[1], e2 = ep[2];

    float lg[L_];
#pragma unroll
    for (int l = 0; l < L_; ++l) lg[l] = b_out[l];
#pragma unroll
    for (int k = 0; k < K_; ++k) {
      float rv = (float)(k < 8 ? e0[k] : (k < 16 ? e1[k - 8] : e2[k - 16]));
#pragma unroll
      for (int l = 0; l < L_; ++l) lg[l] = fmaf(rv, w_out[l * K_ + k], lg[l]);
    }
    float mm = lg[0];
#pragma unroll
    for (int l = 1; l < L_; ++l) mm = fmaxf(mm, lg[l]);
    float s = 0.f;
#pragma unroll
    for (int l = 0; l < L_; ++l) s += expf(lg[l] - mm);

    int t = tgt[((n * D_ + d) * H_ + hh) * W_ + w];
    float lt = lg[0];
#pragma unroll
    for (int l = 1; l < L_; ++l) lt = (t == l) ? lg[l] : lt;

    float lp = lt - mm - logf(s);
    bco[(size_t)((n * H_ + hh) * W_ + w) * D_ + d] = -lp / 0.69314718055994530942f;
  }
}

// ---------------------------------------------------------------- launch
extern "C" void kernel_launch(void* const* d_in, const int* in_sizes, int n_in,
                              void* d_out, int out_size, void* d_ws, size_t ws_size,
                              hipStream_t stream) {
  const float* x       = (const float*)d_in[0];
  const float* centers = (const float*)d_in[1];
  const float* w0      = (const float*)d_in[2];
  const float* b0      = (const float*)d_in[3];
  const float* w1      = (const float*)d_in[4];
  const float* b1      = (const float*)d_in[5];
  const float* w2      = (const float*)d_in[6];
  const float* b2      = (const float*)d_in[7];
  const float* w_out   = (const float*)d_in[8];
  const float* b_out   = (const float*)d_in[9];
  float* out = (float*)d_out;

  char* ws = (char*)d_ws;
  float* q    = (float*)(ws + OFF_Q);
  int*   tg   = (int*)(ws + OFF_TGT);
  f16*   h0f  = (f16*)(ws + OFF_H0);
  f16*   h1f  = (f16*)(ws + OFF_H1);
  float* w0p  = (float*)(ws + OFF_W0P);
  f16*   w1B  = (f16*)(ws + OFF_W1B);
  f16*   w2B  = (f16*)(ws + OFF_W2B);

  hipLaunchKernelGGL(pack_weights_k, dim3(1), dim3(256), 0, stream,
                     w0, w1, w2, w0p, w1B, w2B);
  hipLaunchKernelGGL(quantize_k, dim3(4096), dim3(256), 0, stream,
                     x, centers, out, q, tg);
  hipLaunchKernelGGL(conv0_k, dim3(4096), dim3(256), 0, stream,
                     q, w0p, b0, centers, h0f);
  hipLaunchKernelGGL(conv1_mfma_k, dim3(4096), dim3(512), 0, stream,
                     h0f, w1B, b1, h1f);
  hipLaunchKernelGGL(conv2_mfma_k, dim3(4096), dim3(512), 0, stream,
                     h1f, h0f, w2B, b2, w_out, b_out, tg, out + 1048576);
}

// Round 6
// 197.656 us; speedup vs baseline: 3.2181x; 1.1132x over previous
//
#include <hip/hip_runtime.h>
#include <cstddef>

typedef _Float16 f16;
typedef _Float16 f16x8 __attribute__((ext_vector_type(8)));
typedef float f32x16 __attribute__((ext_vector_type(16)));

#define N_ 4
#define D_ 16
#define H_ 128
#define W_ 128
#define K_ 24
#define L_ 6
#define NTAP_A 13

// workspace byte offsets
#define OFF_Q    0ull          // f32 [n][d][h][w]
#define OFF_TGT  4194304ull    // i32 [n][d][h][w]
#define OFF_H0   8388608ull    // f16 [n][d][h][w][24]
#define OFF_H1   58720256ull   // f16 [n][d][h][w][24]
#define OFF_W0P  109051904ull  // f32 [13][24]
#define OFF_W1B  109053952ull  // f16 fragments, 10752 halves
#define OFF_W2B  109075456ull

// LDS geometry (bytes). A-tile: 19 rows (plane d-1: rows h-1..h+8 -> r0..9,
// plane d: rows h-1..h+7 -> r10..18), each row 132 slots * 48B.
#define AROW_B 6336
#define A_BYTES 120384         // 19 * 6336
#define B_BYTES 21504          // 21 chunks * 1024B
#define SMEM_BYTES 141888

// A-tile byte offset for chunk (p,c), lane-half g (output-row hs*6336 added
// at runtime). Chunk covers taps 2p,2p+1 (mask-B raster), 8-ci blocks.
__host__ __device__ constexpr int aoff(int p, int c, int g) {
  int idx8 = 2 * c + g;
  int ts = idx8 >= 3 ? 1 : 0;
  int t = 2 * p + ts;            // raster tap 0..13
  int cb = idx8 - 3 * ts;        // ci block of 8
  int dz = t / 9 - 1;
  int rr = t % 9;
  int dy = rr / 3 - 1;
  int dx = rr % 3 - 1;
  int rowb = (dz < 0) ? (dy + 1) : (10 + dy + 1);
  return rowb * AROW_B + (dx + 1) * 48 + cb * 16;
}

// ---------------------------------------------------------------- pack weights
__global__ void pack_weights_k(const float* __restrict__ w0,
                               const float* __restrict__ w1,
                               const float* __restrict__ w2,
                               float* __restrict__ w0p,
                               f16* __restrict__ w1B,
                               f16* __restrict__ w2B) {
  int gid = blockIdx.x * 256 + threadIdx.x;
  for (int i = gid; i < NTAP_A * K_; i += 2048) {
    int co = i % K_;
    int t  = i / K_;
    w0p[t * K_ + co] = w0[co * 27 + t];
  }
  // B fragments: halves idx = chunk*512 + g*256 + n*8 + j
  for (int i = gid; i < 2 * 10752; i += 2048) {
    int sel = i / 10752;
    int idx = i % 10752;
    int chunk = idx / 512;
    int r = idx % 512;
    int g = r / 256;
    int n = (r % 256) / 8;
    int j = r % 8;
    int p = chunk / 3, c = chunk % 3;
    int idx8 = 2 * c + g;
    int ts = idx8 >= 3 ? 1 : 0;
    int t = 2 * p + ts;
    int ci = (idx8 - 3 * ts) * 8 + j;
    const float* w = sel ? w2 : w1;
    float v = (n < K_) ? w[(n * K_ + ci) * 27 + t] : 0.f;
    (sel ? w2B : w1B)[idx] = (f16)v;
  }
}

// ---------------------------------------------------------------- quantize
__global__ __launch_bounds__(256) void quantize_k(
    const float* __restrict__ x, const float* __restrict__ centers,
    float* __restrict__ qbar_out, float* __restrict__ q,
    int* __restrict__ tgt) {
  int idx = blockIdx.x * 256 + threadIdx.x;  // over [n][c][h][w]
  int w = idx & 127;
  int h = (idx >> 7) & 127;
  int c = (idx >> 14) & 15;
  int n = idx >> 18;

  float cs[L_];
#pragma unroll
  for (int l = 0; l < L_; ++l) cs[l] = centers[l];

  int xi = ((n * H_ + h) * W_ + w) * D_ + c;  // NHWC
  float xv = x[xi];

  float dv[L_];
  float dmin = 3.4e38f;
  int sym = 0;
#pragma unroll
  for (int l = 0; l < L_; ++l) {
    float df = xv - cs[l];
    float d = df * df;
    dv[l] = d;
    if (d < dmin) { dmin = d; sym = l; }
  }
  float e[L_];
  float s = 0.f;
#pragma unroll
  for (int l = 0; l < L_; ++l) {
    e[l] = expf(dmin - dv[l]);
    s += e[l];
  }
  float qsoft = 0.f;
#pragma unroll
  for (int l = 0; l < L_; ++l) qsoft += (e[l] / s) * cs[l];

  float qhard = cs[sym];
  float qb = qsoft + (qhard - qsoft);

  qbar_out[xi] = qb;
  q[idx] = qb;  // [n][d][h][w]
  tgt[idx] = sym;
}

// ---------------------------------------------------------------- conv0 (1->24, 13 taps, pad=centers[0]) -> fp16 out
__global__ __launch_bounds__(256) void conv0_k(
    const float* __restrict__ q, const float* __restrict__ w0p,
    const float* __restrict__ b0, const float* __restrict__ centers,
    f16* __restrict__ h0) {
  float pv = centers[0];

  int blk = blockIdx.x;  // 4096 = 64 h-pairs * 16 d * 4 n
  int h2 = blk & 63;
  int d = (blk >> 6) & 15;
  int n = blk >> 10;
  int w = threadIdx.x & 127;
  int h = (h2 << 1) | (threadIdx.x >> 7);

  float acc[K_];
#pragma unroll
  for (int i = 0; i < K_; ++i) acc[i] = b0[i];

  const float* base = q + ((n * D_ + d) * H_ + h) * W_ + w;

#pragma unroll 1
  for (int t = 0; t < NTAP_A; ++t) {
    int dz = t / 9 - 1;
    int r = t % 9;
    int dy = r / 3 - 1;
    int dx = r % 3 - 1;
    int hh = h + dy, ww = w + dx, dd = d + dz;
    bool ok = (dd >= 0) && ((unsigned)hh < H_) && ((unsigned)ww < W_);
    float xv = ok ? base[(dz * H_ + dy) * W_ + dx] : pv;
    const float* wr = w0p + t * K_;
#pragma unroll
    for (int co = 0; co < K_; ++co) acc[co] = fmaf(xv, wr[co], acc[co]);
  }

  union { f16 hv[24]; uint4 u[3]; } u;
#pragma unroll
  for (int i = 0; i < K_; ++i) u.hv[i] = (f16)fmaxf(acc[i], 0.f);
  size_t pos = (size_t)(((n * D_ + d) * H_ + h) * W_ + w);
  uint4* dst = (uint4*)(h0 + pos * K_);
  dst[0] = u.u[0]; dst[1] = u.u[1]; dst[2] = u.u[2];
}

// ---------------------------------------------------------------- MFMA core: stage 19-row A + B, 2 M-tiles/wave
__device__ __forceinline__ void conv_core8(const f16* __restrict__ src,
                                           const f16* __restrict__ wB,
                                           char* smem, int n, int d, int h_base,
                                           f32x16& acc0, f32x16& acc1) {
  const int tid = threadIdx.x;
  // stage A: 19 rows * 384 uint4 of data
  for (int i = tid; i < 7296; i += 1024) {
    int r = i / 384, qq = i % 384;
    int dd = (r < 10) ? d - 1 : d;
    int hh = h_base - 1 + ((r < 10) ? r : r - 10);
    uint4 v = make_uint4(0, 0, 0, 0);
    if (dd >= 0 && (unsigned)hh < (unsigned)H_)
      v = ((const uint4*)(src + (size_t)((n * D_ + dd) * H_ + hh) * 3072))[qq];
    *(uint4*)(smem + r * AROW_B + 48 + qq * 16) = v;
  }
  // halo zero: slots w=-1 (byte 0..47) and w=128 (byte 6192..6239) per row
  if (tid < 114) {
    int r = tid / 6, k = tid % 6;
    int byte = r * AROW_B + (k < 3 ? k * 16 : 6192 + (k - 3) * 16);
    *(uint4*)(smem + byte) = make_uint4(0, 0, 0, 0);
  }
  // stage B (once per 8 output rows)
  {
    const uint4* g = (const uint4*)wB;
    uint4* s = (uint4*)(smem + A_BYTES);
    for (int i = tid; i < 1344; i += 1024) s[i] = g[i];
  }
  __syncthreads();

  const int lane = tid & 63;
  const int wv = tid >> 6;        // 0..15
  const int m = lane & 31;
  const int g01 = lane >> 5;

  // wave's two tiles: positions 64*wv .. 64*wv+63 (same h row)
  const int hs = wv >> 1;
  const int wc0 = (wv & 1) * 64;
  const char* Ab0 = smem + hs * AROW_B + (wc0 + m) * 48;
  const char* Ab1 = Ab0 + 32 * 48;
  const char* Bb = smem + A_BYTES + g01 * 512 + m * 16;

#pragma unroll
  for (int r = 0; r < 16; ++r) { acc0[r] = 0.f; acc1[r] = 0.f; }

#pragma unroll
  for (int p = 0; p < 7; ++p) {
#pragma unroll
    for (int c = 0; c < 3; ++c) {
      const int C0 = aoff(p, c, 0);
      const int C1 = aoff(p, c, 1);
      int off = g01 ? C1 : C0;
      f16x8 b = *(const f16x8*)(Bb + (p * 3 + c) * 1024);
      f16x8 a0 = *(const f16x8*)(Ab0 + off);
      f16x8 a1 = *(const f16x8*)(Ab1 + off);
      acc0 = __builtin_amdgcn_mfma_f32_32x32x16_f16(a0, b, acc0, 0, 0, 0);
      acc1 = __builtin_amdgcn_mfma_f32_32x32x16_f16(a1, b, acc1, 0, 0, 0);
    }
  }
}

// ---------------------------------------------------------------- conv1 (h0 -> h1, relu)
__global__ __launch_bounds__(1024, 1) void conv1_mfma_k(
    const f16* __restrict__ src, const f16* __restrict__ wB,
    const float* __restrict__ bias, f16* __restrict__ dst) {
  __shared__ __align__(16) char smem[SMEM_BYTES];

  int blk = blockIdx.x;          // 1024 = 16 hb * 16 d * 4 n
  int hb = blk & 15;
  int d = (blk >> 4) & 15;
  int n = blk >> 8;
  int h_base = hb * 8;

  f32x16 acc0, acc1;
  conv_core8(src, wB, smem, n, d, h_base, acc0, acc1);

  const int lane = threadIdx.x & 63;
  const int wv = threadIdx.x >> 6;
  const int m = lane & 31;
  const int g01 = lane >> 5;

  __syncthreads();  // A dead; reuse as E
  f16* ldsE = (f16*)smem;
  if (m < K_) {
    float bv = bias[m];
#pragma unroll
    for (int tt = 0; tt < 2; ++tt) {
      const f32x16& A = tt ? acc1 : acc0;
#pragma unroll
      for (int r = 0; r < 16; ++r) {
        int mrow = (r & 3) + 8 * (r >> 2) + 4 * g01;
        int pos = (2 * wv + tt) * 32 + mrow;
        ldsE[pos * K_ + m] = (f16)fmaxf(A[r] + bv, 0.f);
      }
    }
  }
  __syncthreads();
  {
    uint4* g = (uint4*)(dst + (size_t)((n * D_ + d) * H_ + h_base) * 3072);
    const uint4* s = (const uint4*)smem;
    for (int i = threadIdx.x; i < 3072; i += 1024) g[i] = s[i];
  }
}

// ---------------------------------------------------------------- conv2 + residual + relu + logits + bitcost
__global__ __launch_bounds__(1024, 1) void conv2_mfma_k(
    const f16* __restrict__ h1, const f16* __restrict__ h0,
    const f16* __restrict__ wB, const float* __restrict__ bias,
    const float* __restrict__ w_out, const float* __restrict__ b_out,
    const int* __restrict__ tgt, float* __restrict__ bco) {
  __shared__ __align__(16) char smem[SMEM_BYTES];

  int blk = blockIdx.x;
  int hb = blk & 15;
  int d = (blk >> 4) & 15;
  int n = blk >> 8;
  int h_base = hb * 8;

  f32x16 acc0, acc1;
  conv_core8(h1, wB, smem, n, d, h_base, acc0, acc1);

  const int lane = threadIdx.x & 63;
  const int wv = threadIdx.x >> 6;
  const int m = lane & 31;
  const int g01 = lane >> 5;

  __syncthreads();  // A dead; reuse as f32 E, row stride 28 (conflict-free)
  float* Ef = (float*)smem;
  if (m < K_) {
    float bv = bias[m];
#pragma unroll
    for (int tt = 0; tt < 2; ++tt) {
      const f32x16& A = tt ? acc1 : acc0;
#pragma unroll
      for (int r = 0; r < 16; ++r) {
        int mrow = (r & 3) + 8 * (r >> 2) + 4 * g01;
        int pos = (2 * wv + tt) * 32 + mrow;
        Ef[pos * 28 + m] = A[r] + bv;
      }
    }
  }
  __syncthreads();

  {
    int pos = threadIdx.x;             // 0..1023
    int hh = h_base + (pos >> 7);
    int w = pos & 127;

    size_t gpos = (size_t)((n * D_ + d) * H_ + h_base) * W_ + pos;
    const f16x8* hp = (const f16x8*)(h0 + gpos * K_);
    f16x8 e0 = hp[0], e1 = hp[1], e2 = hp[2];

    const float* ef = Ef + pos * 28;
    float vals[K_];
#pragma unroll
    for (int k = 0; k < K_; ++k) {
      float h0v = (float)(k < 8 ? e0[k] : (k < 16 ? e1[k - 8] : e2[k - 16]));
      vals[k] = fmaxf(ef[k] + h0v, 0.f);
    }

    float lg[L_];
#pragma unroll
    for (int l = 0; l < L_; ++l) lg[l] = b_out[l];
#pragma unroll
    for (int k = 0; k < K_; ++k) {
      float rv = vals[k];
#pragma unroll
      for (int l = 0; l < L_; ++l) lg[l] = fmaf(rv, w_out[l * K_ + k], lg[l]);
    }
    float mm = lg[0];
#pragma unroll
    for (int l = 1; l < L_; ++l) mm = fmaxf(mm, lg[l]);
    float s = 0.f;
#pragma unroll
    for (int l = 0; l < L_; ++l) s += expf(lg[l] - mm);

    int t = tgt[gpos];
    float lt = lg[0];
#pragma unroll
    for (int l = 1; l < L_; ++l) lt = (t == l) ? lg[l] : lt;

    float lp = lt - mm - logf(s);
    bco[(size_t)((n * H_ + hh) * W_ + w) * D_ + d] = -lp / 0.69314718055994530942f;
  }
}

// ---------------------------------------------------------------- launch
extern "C" void kernel_launch(void* const* d_in, const int* in_sizes, int n_in,
                              void* d_out, int out_size, void* d_ws, size_t ws_size,
                              hipStream_t stream) {
  const float* x       = (const float*)d_in[0];
  const float* centers = (const float*)d_in[1];
  const float* w0      = (const float*)d_in[2];
  const float* b0      = (const float*)d_in[3];
  const float* w1      = (const float*)d_in[4];
  const float* b1      = (const float*)d_in[5];
  const float* w2      = (const float*)d_in[6];
  const float* b2      = (const float*)d_in[7];
  const float* w_out   = (const float*)d_in[8];
  const float* b_out   = (const float*)d_in[9];
  float* out = (float*)d_out;

  char* ws = (char*)d_ws;
  float* q    = (float*)(ws + OFF_Q);
  int*   tg   = (int*)(ws + OFF_TGT);
  f16*   h0f  = (f16*)(ws + OFF_H0);
  f16*   h1f  = (f16*)(ws + OFF_H1);
  float* w0p  = (float*)(ws + OFF_W0P);
  f16*   w1B  = (f16*)(ws + OFF_W1B);
  f16*   w2B  = (f16*)(ws + OFF_W2B);

  hipLaunchKernelGGL(pack_weights_k, dim3(8), dim3(256), 0, stream,
                     w0, w1, w2, w0p, w1B, w2B);
  hipLaunchKernelGGL(quantize_k, dim3(4096), dim3(256), 0, stream,
                     x, centers, out, q, tg);
  hipLaunchKernelGGL(conv0_k, dim3(4096), dim3(256), 0, stream,
                     q, w0p, b0, centers, h0f);
  hipLaunchKernelGGL(conv1_mfma_k, dim3(1024), dim3(1024), 0, stream,
                     h0f, w1B, b1, h1f);
  hipLaunchKernelGGL(conv2_mfma_k, dim3(1024), dim3(1024), 0, stream,
                     h1f, h0f, w2B, b2, w_out, b_out, tg, out + 1048576);
}